// Round 3
// baseline (208.357 us; speedup 1.0000x reference)
//
#include <hip/hip_runtime.h>
#include <hip/hip_bf16.h>
#include <math.h>

// Problem constants
#define NB   2048     // batch
#define ND   1024     // dim (elements; == bytes per row in fp8)
#define INV_TEMP 10.0f
#define LAMBDA_CS 0.5f
#define GEMM_BLOCKS 1552

using intx4   = __attribute__((ext_vector_type(4))) int;
using intx8   = __attribute__((ext_vector_type(8))) int;
using floatx4 = __attribute__((ext_vector_type(4))) float;

__device__ __forceinline__ int pack4_fp8(float a, float b, float c, float d) {
  int p = __builtin_amdgcn_cvt_pk_fp8_f32(a, b, 0, false);   // bytes 0,1
  p     = __builtin_amdgcn_cvt_pk_fp8_f32(c, d, p, true);    // bytes 2,3
  return p;
}

// ---------------------------------------------------------------------------
// Kernel 1: fused row L2-normalize -> fp8 M (8192 x 1024, t-order {e,k,et,kt})
// + cs-reg partial per row + zero rowsum/counter for kernel 2.
// ---------------------------------------------------------------------------
__global__ __launch_bounds__(256) void k_prep(
    const float* __restrict__ e, const float* __restrict__ k,
    const float* __restrict__ et, const float* __restrict__ kt,
    const float* __restrict__ ratios,
    unsigned char* __restrict__ M, float* __restrict__ reg_partial,
    float* __restrict__ rowsum, unsigned* __restrict__ counter)
{
  const int b = blockIdx.x, tid = threadIdx.x;
  const int wave = tid >> 6, lane = tid & 63;

  if (b < 16) rowsum[b * 256 + tid] = 0.0f;
  if (b == 16 && tid == 0) *counter = 0u;

  float4 ve  = ((const float4*)(e  + (size_t)b * ND))[tid];
  float4 vk  = ((const float4*)(k  + (size_t)b * ND))[tid];
  float4 vet = ((const float4*)(et + (size_t)b * ND))[tid];
  float4 vkt = ((const float4*)(kt + (size_t)b * ND))[tid];

  float s0 = ve.x*ve.x + ve.y*ve.y + ve.z*ve.z + ve.w*ve.w;
  float s1 = vk.x*vk.x + vk.y*vk.y + vk.z*vk.z + vk.w*vk.w;
  float s2 = vet.x*vet.x + vet.y*vet.y + vet.z*vet.z + vet.w*vet.w;
  float s3 = vkt.x*vkt.x + vkt.y*vkt.y + vkt.z*vkt.z + vkt.w*vkt.w;
  #pragma unroll
  for (int o = 1; o < 64; o <<= 1) {
    s0 += __shfl_xor(s0, o); s1 += __shfl_xor(s1, o);
    s2 += __shfl_xor(s2, o); s3 += __shfl_xor(s3, o);
  }
  __shared__ float red[4][4];
  if (lane == 0) { red[wave][0] = s0; red[wave][1] = s1; red[wave][2] = s2; red[wave][3] = s3; }
  __syncthreads();
  const float ie  = 1.0f / sqrtf(red[0][0] + red[1][0] + red[2][0] + red[3][0]);
  const float ik  = 1.0f / sqrtf(red[0][1] + red[1][1] + red[2][1] + red[3][1]);
  const float iet = 1.0f / sqrtf(red[0][2] + red[1][2] + red[2][2] + red[3][2]);
  const float ikt = 1.0f / sqrtf(red[0][3] + red[1][3] + red[2][3] + red[3][3]);

  // write normalized fp8 rows, t order {0:e, 1:k, 2:et, 3:kt}
  *(int*)(M + ((size_t)0 * NB + b) * ND + tid * 4) =
      pack4_fp8(ve.x * ie,  ve.y * ie,  ve.z * ie,  ve.w * ie);
  *(int*)(M + ((size_t)1 * NB + b) * ND + tid * 4) =
      pack4_fp8(vk.x * ik,  vk.y * ik,  vk.z * ik,  vk.w * ik);
  *(int*)(M + ((size_t)2 * NB + b) * ND + tid * 4) =
      pack4_fp8(vet.x * iet, vet.y * iet, vet.z * iet, vet.w * iet);
  *(int*)(M + ((size_t)3 * NB + b) * ND + tid * 4) =
      pack4_fp8(vkt.x * ikt, vkt.y * ikt, vkt.z * ikt, vkt.w * ikt);

  // cs-reg partial (exact fp32)
  const float r = ratios[b], rm = 1.0f - r;
  float a1 = 0.f, a2 = 0.f;
  {
    float en, kn, d1, d2;
    en = ve.x*ie; kn = vk.x*ik;
    d1 = vet.x*iet - (r*en + rm*kn); d2 = vkt.x*ikt - (rm*en + r*kn);
    a1 += d1*d1; a2 += d2*d2;
    en = ve.y*ie; kn = vk.y*ik;
    d1 = vet.y*iet - (r*en + rm*kn); d2 = vkt.y*ikt - (rm*en + r*kn);
    a1 += d1*d1; a2 += d2*d2;
    en = ve.z*ie; kn = vk.z*ik;
    d1 = vet.z*iet - (r*en + rm*kn); d2 = vkt.z*ikt - (rm*en + r*kn);
    a1 += d1*d1; a2 += d2*d2;
    en = ve.w*ie; kn = vk.w*ik;
    d1 = vet.w*iet - (r*en + rm*kn); d2 = vkt.w*ikt - (rm*en + r*kn);
    a1 += d1*d1; a2 += d2*d2;
  }
  #pragma unroll
  for (int o = 1; o < 64; o <<= 1) { a1 += __shfl_xor(a1, o); a2 += __shfl_xor(a2, o); }
  __shared__ float red2[4][2];
  if (lane == 0) { red2[wave][0] = a1; red2[wave][1] = a2; }
  __syncthreads();
  if (tid == 0) {
    float t1 = red2[0][0] + red2[1][0] + red2[2][0] + red2[3][0];
    float t2 = red2[0][1] + red2[1][1] + red2[2][1] + red2[3][1];
    reg_partial[b] = sqrtf(t1) + sqrtf(t2);
  }
}

// ---------------------------------------------------------------------------
// Kernel 2: fused MX-fp8 NT-GEMM + exp + row-sum atomics + diagonal capture +
// last-block final reduction. Symmetric left half: only upper-tri blocks.
//   mfma_scale_f32_16x16x128_f8f6f4, unit scales (e8m0=127 -> 1.0).
//   128x128 tile, BK=128 (8 K-iterations), 256 threads (2x2 waves of 64x64).
// ---------------------------------------------------------------------------
__global__ __launch_bounds__(256) void k_gemm(
    const unsigned char* __restrict__ M,
    float* __restrict__ rowsum,        // [4096], zeroed by k_prep
    float* __restrict__ diag,          // [2][4][2048]; [1][0] unused (mirror)
    const float* __restrict__ reg_partial,
    unsigned* __restrict__ counter,
    float* __restrict__ out)
{
  __shared__ __align__(16) unsigned char As[128 * 128];
  __shared__ __align__(16) unsigned char Bs[128 * 128];
  __shared__ float redR[256];
  __shared__ float redC[256];
  __shared__ unsigned s_rank;

  // decode (bx, by): 1024 right-half blocks + 528 upper-tri left-half blocks
  int bx, by;
  {
    int idx = blockIdx.x;
    if (idx < 1024) { by = idx >> 5; bx = 32 + (idx & 31); }
    else {
      int t = idx - 1024; by = 0;
      while (t >= 32 - by) { t -= 32 - by; ++by; }
      bx = by + t;
    }
  }
  const bool sym = (bx < 32) && (bx > by);
  const int j0 = bx * 128;
  const int i0 = by * 128;

  const int tid  = threadIdx.x;
  const int wave = tid >> 6;
  const int lane = tid & 63;
  const int q = lane >> 4;       // quad 0..3
  const int m = lane & 15;       // row/col within 16
  const int wrow = (wave >> 1) * 64;
  const int wcol = (wave & 1) * 64;

  floatx4 acc[4][4] = {};

  // staging: chunk = 8 rows x 128B; wave w stages chunks 4w..4w+3 of A and B.
  // lane -> row lane>>3 within chunk, 16B sub-chunk XOR-swizzled by (row&7)
  // so fragment ds_read_b128 is only 2-way bank-aliased (free, m136).
  int sOffA[4];  // byte offset within tile (row*1024 global stride handled below)
  int ldsOff[4];
  #pragma unroll
  for (int x = 0; x < 4; ++x) {
    const int r = (wave * 4 + x) * 8 + (lane >> 3);   // 0..127
    const int c = (lane & 7) ^ (r & 7);
    sOffA[x]  = r * ND + c * 16;      // global byte offset within tile
    ldsOff[x] = (wave * 4 + x) * 1024;
  }

  const unsigned char* gA = M + (size_t)i0 * ND;
  const unsigned char* gB = M + (size_t)j0 * ND;

  // fragment LDS byte offsets (two 16B chunks per operand, XOR-swizzled)
  int aoff0[4], aoff1[4], boff0[4], boff1[4];
  #pragma unroll
  for (int x = 0; x < 4; ++x) {
    const int ra = wrow + x * 16 + m;
    aoff0[x] = ra * 128 + ((2 * q)     ^ (ra & 7)) * 16;
    aoff1[x] = ra * 128 + ((2 * q + 1) ^ (ra & 7)) * 16;
    const int rb = wcol + x * 16 + m;
    boff0[x] = rb * 128 + ((2 * q)     ^ (rb & 7)) * 16;
    boff1[x] = rb * 128 + ((2 * q + 1) ^ (rb & 7)) * 16;
  }

  for (int it = 0; it < 8; ++it) {
    const int koff = it * 128;
    __syncthreads();
    #pragma unroll
    for (int x = 0; x < 4; ++x) {
      __builtin_amdgcn_global_load_lds(
          (const __attribute__((address_space(1))) unsigned int*)(gA + sOffA[x] + koff),
          (__attribute__((address_space(3))) unsigned int*)&As[ldsOff[x]], 16, 0, 0);
      __builtin_amdgcn_global_load_lds(
          (const __attribute__((address_space(1))) unsigned int*)(gB + sOffA[x] + koff),
          (__attribute__((address_space(3))) unsigned int*)&Bs[ldsOff[x]], 16, 0, 0);
    }
    __syncthreads();

    intx8 af[4], bf[4];
    #pragma unroll
    for (int x = 0; x < 4; ++x) {
      intx4 lo = *(const intx4*)&As[aoff0[x]];
      intx4 hi = *(const intx4*)&As[aoff1[x]];
      af[x][0] = lo[0]; af[x][1] = lo[1]; af[x][2] = lo[2]; af[x][3] = lo[3];
      af[x][4] = hi[0]; af[x][5] = hi[1]; af[x][6] = hi[2]; af[x][7] = hi[3];
      lo = *(const intx4*)&Bs[boff0[x]];
      hi = *(const intx4*)&Bs[boff1[x]];
      bf[x][0] = lo[0]; bf[x][1] = lo[1]; bf[x][2] = lo[2]; bf[x][3] = lo[3];
      bf[x][4] = hi[0]; bf[x][5] = hi[1]; bf[x][6] = hi[2]; bf[x][7] = hi[3];
    }
    #pragma unroll
    for (int mi = 0; mi < 4; ++mi)
      #pragma unroll
      for (int ni = 0; ni < 4; ++ni)
        acc[mi][ni] = __builtin_amdgcn_mfma_scale_f32_16x16x128_f8f6f4(
            af[mi], bf[ni], acc[mi][ni],
            0 /*cbsz: A=fp8 e4m3*/, 0 /*blgp: B=fp8 e4m3*/,
            0, 0x7f7f7f7f,   // scale_a opsel, unit scales (e8m0 127 = 1.0)
            0, 0x7f7f7f7f);  // scale_b
  }

  // Epilogue. C/D layout (shape-determined): col = lane&15, row = q*4 + reg
  float colAcc[4] = {0.f, 0.f, 0.f, 0.f};
  #pragma unroll
  for (int mi = 0; mi < 4; ++mi) {
    #pragma unroll
    for (int r = 0; r < 4; ++r) {
      const int ig = i0 + wrow + mi * 16 + q * 4 + r;
      float s = 0.f;
      #pragma unroll
      for (int ni = 0; ni < 4; ++ni) {
        float v = __expf(acc[mi][ni][r] * INV_TEMP);
        s += v;
        colAcc[ni] += v;
        const int jg = j0 + wcol + ni * 16 + m;
        if ((jg & (NB - 1)) == (ig & (NB - 1))) {
          diag[(((ig >> 11) << 2) + (jg >> 11)) * NB + (ig & (NB - 1))] = v;
        }
      }
      s += __shfl_xor(s, 1);
      s += __shfl_xor(s, 2);
      s += __shfl_xor(s, 4);
      s += __shfl_xor(s, 8);
      if (m == 0) redR[(wave & 1) * 128 + wrow + mi * 16 + q * 4 + r] = s;
    }
  }
  #pragma unroll
  for (int ni = 0; ni < 4; ++ni) {
    float c = colAcc[ni];
    c += __shfl_xor(c, 16);
    c += __shfl_xor(c, 32);
    if (q == 0) redC[(wave >> 1) * 128 + wcol + ni * 16 + m] = c;
  }
  __syncthreads();
  if (tid < 128) {
    atomicAdd(&rowsum[i0 + tid], redR[tid] + redR[128 + tid]);
    if (sym)
      atomicAdd(&rowsum[j0 + tid], redC[tid] + redC[128 + tid]);
  }

  // completion: last finished block computes the final scalars
  __syncthreads();   // drains all waves' stores/atomics (vmcnt(0) before barrier)
  if (tid == 0) {
    __threadfence(); // device-scope release (L2 writeback of diag stores)
    s_rank = __hip_atomic_fetch_add(counter, 1u, __ATOMIC_ACQ_REL,
                                    __HIP_MEMORY_SCOPE_AGENT);
  }
  __syncthreads();
  if (s_rank == GEMM_BLOCKS - 1) {
    float l = 0.f, g = 0.f;
    #pragma unroll
    for (int i = 0; i < 8; ++i) {
      const int n = tid + i * 256;
      float se = __hip_atomic_load(&rowsum[n],        __ATOMIC_RELAXED, __HIP_MEMORY_SCOPE_AGENT);
      float sk = __hip_atomic_load(&rowsum[2048 + n], __ATOMIC_RELAXED, __HIP_MEMORY_SCOPE_AGENT);
      float d_ee  = __hip_atomic_load(&diag[0 * NB + n], __ATOMIC_RELAXED, __HIP_MEMORY_SCOPE_AGENT);
      float d_ek  = __hip_atomic_load(&diag[1 * NB + n], __ATOMIC_RELAXED, __HIP_MEMORY_SCOPE_AGENT);
      float d_eet = __hip_atomic_load(&diag[2 * NB + n], __ATOMIC_RELAXED, __HIP_MEMORY_SCOPE_AGENT);
      float d_ekt = __hip_atomic_load(&diag[3 * NB + n], __ATOMIC_RELAXED, __HIP_MEMORY_SCOPE_AGENT);
      float d_kk  = __hip_atomic_load(&diag[5 * NB + n], __ATOMIC_RELAXED, __HIP_MEMORY_SCOPE_AGENT);
      float d_ket = __hip_atomic_load(&diag[6 * NB + n], __ATOMIC_RELAXED, __HIP_MEMORY_SCOPE_AGENT);
      float d_kkt = __hip_atomic_load(&diag[7 * NB + n], __ATOMIC_RELAXED, __HIP_MEMORY_SCOPE_AGENT);
      float num_e = d_ek + d_eet + d_ekt;
      float den_e = se - d_ee;
      float num_k = d_ek + d_ket + d_kkt;   // k.e diag == e.k diag (mirror)
      float den_k = sk - d_kk;
      l += logf(den_e / num_e) + logf(den_k / num_k);
      g += reg_partial[n];
    }
    #pragma unroll
    for (int o = 1; o < 64; o <<= 1) { l += __shfl_xor(l, o); g += __shfl_xor(g, o); }
    if ((tid & 63) == 0) { redR[tid >> 6] = l; redC[tid >> 6] = g; }
    __syncthreads();
    if (tid == 0) {
      float contrastive = (redR[0] + redR[1] + redR[2] + redR[3]) * (1.0f / (2.0f * NB));
      float cs = (redC[0] + redC[1] + redC[2] + redC[3]) * (1.0f / NB);
      out[0] = contrastive + LAMBDA_CS * cs;
      out[1] = contrastive;
      out[2] = cs;
    }
  }
}

// ---------------------------------------------------------------------------
extern "C" void kernel_launch(void* const* d_in, const int* in_sizes, int n_in,
                              void* d_out, int out_size, void* d_ws, size_t ws_size,
                              hipStream_t stream) {
  const float* english = (const float*)d_in[0];
  const float* etok    = (const float*)d_in[1];
  const float* ktoe    = (const float*)d_in[2];
  const float* korean  = (const float*)d_in[3];
  const float* ratios  = (const float*)d_in[4];

  char* ws = (char*)d_ws;
  const size_t OFF_M    = 0;                                   // 8192*1024 = 8 MB
  const size_t OFF_RS   = OFF_M + (size_t)8192 * 1024;         // 4096*4
  const size_t OFF_DIAG = OFF_RS + 4096 * sizeof(float);       // 8*2048*4
  const size_t OFF_REG  = OFF_DIAG + 8 * NB * sizeof(float);   // 2048*4
  const size_t OFF_CNT  = OFF_REG + NB * sizeof(float);        // 4

  unsigned char* M    = (unsigned char*)(ws + OFF_M);
  float* rowsum       = (float*)(ws + OFF_RS);
  float* diag         = (float*)(ws + OFF_DIAG);
  float* reg_partial  = (float*)(ws + OFF_REG);
  unsigned* counter   = (unsigned*)(ws + OFF_CNT);

  k_prep<<<dim3(NB), 256, 0, stream>>>(english, korean, etok, ktoe, ratios,
                                       M, reg_partial, rowsum, counter);
  k_gemm<<<dim3(GEMM_BLOCKS), 256, 0, stream>>>(M, rowsum, diag, reg_partial,
                                                counter, (float*)d_out);
}

// Round 4
// 181.169 us; speedup vs baseline: 1.1501x; 1.1501x over previous
//
#include <hip/hip_runtime.h>
#include <hip/hip_bf16.h>
#include <math.h>

// Problem constants
#define NB   2048     // batch
#define ND   1024     // dim (elements; == bytes per row in fp8)
#define INV_TEMP 10.0f
#define LAMBDA_CS 0.5f
#define GEMM_BLOCKS 1552

using floatx4 = __attribute__((ext_vector_type(4))) float;
using longx2  = __attribute__((ext_vector_type(2))) long;

__device__ __forceinline__ int pack4_fp8(float a, float b, float c, float d) {
  int p = __builtin_amdgcn_cvt_pk_fp8_f32(a, b, 0, false);   // bytes 0,1
  p     = __builtin_amdgcn_cvt_pk_fp8_f32(c, d, p, true);    // bytes 2,3
  return p;
}

// ---------------------------------------------------------------------------
// Kernel 1: fused row L2-normalize -> fp8 M (8192 x 1024, t-order {e,k,et,kt})
// with COLUMN PERMUTATION per 64-col group: k = s*32+q*8+j  ->  c' = q*16+s*8+j
// (so one 16B LDS read gives a lane's quad-chunk for both K=32 steps of a
//  BK=64 tile). Also: cs-reg partial per row + zero rowsum/counter.
// ---------------------------------------------------------------------------
__global__ __launch_bounds__(256) void k_prep(
    const float* __restrict__ e, const float* __restrict__ k,
    const float* __restrict__ et, const float* __restrict__ kt,
    const float* __restrict__ ratios,
    unsigned char* __restrict__ M, float* __restrict__ reg_partial,
    float* __restrict__ rowsum, unsigned* __restrict__ counter)
{
  const int b = blockIdx.x, tid = threadIdx.x;
  const int wave = tid >> 6, lane = tid & 63;

  if (b < 16) rowsum[b * 256 + tid] = 0.0f;
  if (b == 16 && tid == 0) *counter = 0u;

  float4 ve  = ((const float4*)(e  + (size_t)b * ND))[tid];
  float4 vk  = ((const float4*)(k  + (size_t)b * ND))[tid];
  float4 vet = ((const float4*)(et + (size_t)b * ND))[tid];
  float4 vkt = ((const float4*)(kt + (size_t)b * ND))[tid];

  float s0 = ve.x*ve.x + ve.y*ve.y + ve.z*ve.z + ve.w*ve.w;
  float s1 = vk.x*vk.x + vk.y*vk.y + vk.z*vk.z + vk.w*vk.w;
  float s2 = vet.x*vet.x + vet.y*vet.y + vet.z*vet.z + vet.w*vet.w;
  float s3 = vkt.x*vkt.x + vkt.y*vkt.y + vkt.z*vkt.z + vkt.w*vkt.w;
  #pragma unroll
  for (int o = 1; o < 64; o <<= 1) {
    s0 += __shfl_xor(s0, o); s1 += __shfl_xor(s1, o);
    s2 += __shfl_xor(s2, o); s3 += __shfl_xor(s3, o);
  }
  __shared__ float red[4][4];
  if (lane == 0) { red[wave][0] = s0; red[wave][1] = s1; red[wave][2] = s2; red[wave][3] = s3; }
  __syncthreads();
  const float ie  = 1.0f / sqrtf(red[0][0] + red[1][0] + red[2][0] + red[3][0]);
  const float ik  = 1.0f / sqrtf(red[0][1] + red[1][1] + red[2][1] + red[3][1]);
  const float iet = 1.0f / sqrtf(red[0][2] + red[1][2] + red[2][2] + red[3][2]);
  const float ikt = 1.0f / sqrtf(red[0][3] + red[1][3] + red[2][3] + red[3][3]);

  // permuted destination column for this thread's 4 consecutive k's
  const int k4 = tid * 4;
  const int cp = (k4 & ~63) | (((k4 >> 3) & 3) << 4) | (((k4 >> 5) & 1) << 3) | (k4 & 7);

  *(int*)(M + ((size_t)0 * NB + b) * ND + cp) =
      pack4_fp8(ve.x * ie,  ve.y * ie,  ve.z * ie,  ve.w * ie);
  *(int*)(M + ((size_t)1 * NB + b) * ND + cp) =
      pack4_fp8(vk.x * ik,  vk.y * ik,  vk.z * ik,  vk.w * ik);
  *(int*)(M + ((size_t)2 * NB + b) * ND + cp) =
      pack4_fp8(vet.x * iet, vet.y * iet, vet.z * iet, vet.w * iet);
  *(int*)(M + ((size_t)3 * NB + b) * ND + cp) =
      pack4_fp8(vkt.x * ikt, vkt.y * ikt, vkt.z * ikt, vkt.w * ikt);

  // cs-reg partial (exact fp32)
  const float r = ratios[b], rm = 1.0f - r;
  float a1 = 0.f, a2 = 0.f;
  {
    float en, kn, d1, d2;
    en = ve.x*ie; kn = vk.x*ik;
    d1 = vet.x*iet - (r*en + rm*kn); d2 = vkt.x*ikt - (rm*en + r*kn);
    a1 += d1*d1; a2 += d2*d2;
    en = ve.y*ie; kn = vk.y*ik;
    d1 = vet.y*iet - (r*en + rm*kn); d2 = vkt.y*ikt - (rm*en + r*kn);
    a1 += d1*d1; a2 += d2*d2;
    en = ve.z*ie; kn = vk.z*ik;
    d1 = vet.z*iet - (r*en + rm*kn); d2 = vkt.z*ikt - (rm*en + r*kn);
    a1 += d1*d1; a2 += d2*d2;
    en = ve.w*ie; kn = vk.w*ik;
    d1 = vet.w*iet - (r*en + rm*kn); d2 = vkt.w*ikt - (rm*en + r*kn);
    a1 += d1*d1; a2 += d2*d2;
  }
  #pragma unroll
  for (int o = 1; o < 64; o <<= 1) { a1 += __shfl_xor(a1, o); a2 += __shfl_xor(a2, o); }
  __shared__ float red2[4][2];
  if (lane == 0) { red2[wave][0] = a1; red2[wave][1] = a2; }
  __syncthreads();
  if (tid == 0) {
    float t1 = red2[0][0] + red2[1][0] + red2[2][0] + red2[3][0];
    float t2 = red2[0][1] + red2[1][1] + red2[2][1] + red2[3][1];
    reg_partial[b] = sqrtf(t1) + sqrtf(t2);
  }
}

// ---------------------------------------------------------------------------
// Kernel 2: fused fp8 NT-GEMM + exp + row-sum + diag + last-block reduction.
//   mfma_f32_16x16x32_fp8_fp8 (i64 operands), BK=64 (16 K-iterations).
//   LDS geometry is byte-identical to the validated R2 bf16 kernel
//   (128 rows x 64 B, 16B-chunk swizzle q^((m>>1)&3): measured 0 conflicts).
//   Symmetric left half: only upper-tri blocks; mirrored column credit.
// ---------------------------------------------------------------------------
__global__ __launch_bounds__(256) void k_gemm(
    const unsigned char* __restrict__ M,
    float* __restrict__ rowsum,        // [4096], zeroed by k_prep
    float* __restrict__ diag,          // [2][4][2048]; [1][0] unused (mirror)
    const float* __restrict__ reg_partial,
    unsigned* __restrict__ counter,
    float* __restrict__ out)
{
  __shared__ __align__(16) unsigned char As[128 * 64];
  __shared__ __align__(16) unsigned char Bs[128 * 64];
  __shared__ float redR[256];
  __shared__ float redC[256];
  __shared__ unsigned s_rank;

  // decode (bx, by): 1024 right-half blocks + 528 upper-tri left-half blocks
  int bx, by;
  {
    int idx = blockIdx.x;
    if (idx < 1024) { by = idx >> 5; bx = 32 + (idx & 31); }
    else {
      int t = idx - 1024; by = 0;
      while (t >= 32 - by) { t -= 32 - by; ++by; }
      bx = by + t;
    }
  }
  const bool sym = (bx < 32) && (bx > by);
  const int j0 = bx * 128;
  const int i0 = by * 128;

  const int tid  = threadIdx.x;
  const int wave = tid >> 6;
  const int lane = tid & 63;
  const int q = lane >> 4;       // quad 0..3
  const int m = lane & 15;       // row/col within 16
  const int wrow = (wave >> 1) * 64;
  const int wcol = (wave & 1) * 64;

  floatx4 acc[4][4] = {};

  // staging: chunk = 16 rows x 64 B = 1024 B; wave w stages chunks {2w,2w+1}
  // of A and B. lane -> row lane>>2, 16B sub-chunk (lane&3) XOR ((srow>>1)&3).
  const int srow = lane >> 2;
  const int scol = (lane & 3) ^ ((srow >> 1) & 3);
  const int c0 = wave * 2, c1 = c0 + 1;

  const unsigned char* gA = M + (size_t)i0 * ND;
  const unsigned char* gB = M + (size_t)j0 * ND;

  // fragment LDS byte offsets (16B per operand-pair, swizzle matches staging)
  int aoff[4], boff[4];
  #pragma unroll
  for (int x = 0; x < 4; ++x) {
    const int sw = (q ^ ((m >> 1) & 3)) * 16;
    aoff[x] = (wrow + x * 16 + m) * 64 + sw;
    boff[x] = (wcol + x * 16 + m) * 64 + sw;
  }

  for (int it = 0; it < 16; ++it) {
    const int koff = it * 64;
    __syncthreads();
    {
      const unsigned char* g = gA + (size_t)(c0 * 16 + srow) * ND + koff + scol * 16;
      __builtin_amdgcn_global_load_lds(
          (const __attribute__((address_space(1))) unsigned int*)g,
          (__attribute__((address_space(3))) unsigned int*)&As[c0 * 1024], 16, 0, 0);
    }
    {
      const unsigned char* g = gA + (size_t)(c1 * 16 + srow) * ND + koff + scol * 16;
      __builtin_amdgcn_global_load_lds(
          (const __attribute__((address_space(1))) unsigned int*)g,
          (__attribute__((address_space(3))) unsigned int*)&As[c1 * 1024], 16, 0, 0);
    }
    {
      const unsigned char* g = gB + (size_t)(c0 * 16 + srow) * ND + koff + scol * 16;
      __builtin_amdgcn_global_load_lds(
          (const __attribute__((address_space(1))) unsigned int*)g,
          (__attribute__((address_space(3))) unsigned int*)&Bs[c0 * 1024], 16, 0, 0);
    }
    {
      const unsigned char* g = gB + (size_t)(c1 * 16 + srow) * ND + koff + scol * 16;
      __builtin_amdgcn_global_load_lds(
          (const __attribute__((address_space(1))) unsigned int*)g,
          (__attribute__((address_space(3))) unsigned int*)&Bs[c1 * 1024], 16, 0, 0);
    }
    __syncthreads();

    longx2 af[4], bf[4];
    #pragma unroll
    for (int x = 0; x < 4; ++x) {
      af[x] = *(const longx2*)&As[aoff[x]];
      bf[x] = *(const longx2*)&Bs[boff[x]];
    }
    #pragma unroll
    for (int mi = 0; mi < 4; ++mi)
      #pragma unroll
      for (int ni = 0; ni < 4; ++ni) {
        acc[mi][ni] = __builtin_amdgcn_mfma_f32_16x16x32_fp8_fp8(
            af[mi][0], bf[ni][0], acc[mi][ni], 0, 0, 0);
        acc[mi][ni] = __builtin_amdgcn_mfma_f32_16x16x32_fp8_fp8(
            af[mi][1], bf[ni][1], acc[mi][ni], 0, 0, 0);
      }
  }

  // Epilogue. C/D layout (dtype-independent): col = lane&15, row = q*4 + reg
  float colAcc[4] = {0.f, 0.f, 0.f, 0.f};
  #pragma unroll
  for (int mi = 0; mi < 4; ++mi) {
    #pragma unroll
    for (int r = 0; r < 4; ++r) {
      const int ig = i0 + wrow + mi * 16 + q * 4 + r;
      float s = 0.f;
      #pragma unroll
      for (int ni = 0; ni < 4; ++ni) {
        float v = __expf(acc[mi][ni][r] * INV_TEMP);
        s += v;
        colAcc[ni] += v;
        const int jg = j0 + wcol + ni * 16 + m;
        if ((jg & (NB - 1)) == (ig & (NB - 1))) {
          diag[(((ig >> 11) << 2) + (jg >> 11)) * NB + (ig & (NB - 1))] = v;
        }
      }
      s += __shfl_xor(s, 1);
      s += __shfl_xor(s, 2);
      s += __shfl_xor(s, 4);
      s += __shfl_xor(s, 8);
      if (m == 0) redR[(wave & 1) * 128 + wrow + mi * 16 + q * 4 + r] = s;
    }
  }
  #pragma unroll
  for (int ni = 0; ni < 4; ++ni) {
    float c = colAcc[ni];
    c += __shfl_xor(c, 16);
    c += __shfl_xor(c, 32);
    if (q == 0) redC[(wave >> 1) * 128 + wcol + ni * 16 + m] = c;
  }
  __syncthreads();
  if (tid < 128) {
    atomicAdd(&rowsum[i0 + tid], redR[tid] + redR[128 + tid]);
    if (sym)
      atomicAdd(&rowsum[j0 + tid], redC[tid] + redC[128 + tid]);
  }

  // completion: last finished block computes the final scalars
  __syncthreads();
  if (tid == 0) {
    __threadfence();
    s_rank = __hip_atomic_fetch_add(counter, 1u, __ATOMIC_ACQ_REL,
                                    __HIP_MEMORY_SCOPE_AGENT);
  }
  __syncthreads();
  if (s_rank == GEMM_BLOCKS - 1) {
    float l = 0.f, g = 0.f;
    #pragma unroll
    for (int i = 0; i < 8; ++i) {
      const int n = tid + i * 256;
      float se = __hip_atomic_load(&rowsum[n],        __ATOMIC_RELAXED, __HIP_MEMORY_SCOPE_AGENT);
      float sk = __hip_atomic_load(&rowsum[2048 + n], __ATOMIC_RELAXED, __HIP_MEMORY_SCOPE_AGENT);
      float d_ee  = __hip_atomic_load(&diag[0 * NB + n], __ATOMIC_RELAXED, __HIP_MEMORY_SCOPE_AGENT);
      float d_ek  = __hip_atomic_load(&diag[1 * NB + n], __ATOMIC_RELAXED, __HIP_MEMORY_SCOPE_AGENT);
      float d_eet = __hip_atomic_load(&diag[2 * NB + n], __ATOMIC_RELAXED, __HIP_MEMORY_SCOPE_AGENT);
      float d_ekt = __hip_atomic_load(&diag[3 * NB + n], __ATOMIC_RELAXED, __HIP_MEMORY_SCOPE_AGENT);
      float d_kk  = __hip_atomic_load(&diag[5 * NB + n], __ATOMIC_RELAXED, __HIP_MEMORY_SCOPE_AGENT);
      float d_ket = __hip_atomic_load(&diag[6 * NB + n], __ATOMIC_RELAXED, __HIP_MEMORY_SCOPE_AGENT);
      float d_kkt = __hip_atomic_load(&diag[7 * NB + n], __ATOMIC_RELAXED, __HIP_MEMORY_SCOPE_AGENT);
      float num_e = d_ek + d_eet + d_ekt;
      float den_e = se - d_ee;
      float num_k = d_ek + d_ket + d_kkt;   // k.e diag == e.k diag (mirror)
      float den_k = sk - d_kk;
      l += logf(den_e / num_e) + logf(den_k / num_k);
      g += reg_partial[n];
    }
    #pragma unroll
    for (int o = 1; o < 64; o <<= 1) { l += __shfl_xor(l, o); g += __shfl_xor(g, o); }
    if ((tid & 63) == 0) { redR[tid >> 6] = l; redC[tid >> 6] = g; }
    __syncthreads();
    if (tid == 0) {
      float contrastive = (redR[0] + redR[1] + redR[2] + redR[3]) * (1.0f / (2.0f * NB));
      float cs = (redC[0] + redC[1] + redC[2] + redC[3]) * (1.0f / NB);
      out[0] = contrastive + LAMBDA_CS * cs;
      out[1] = contrastive;
      out[2] = cs;
    }
  }
}

// ---------------------------------------------------------------------------
extern "C" void kernel_launch(void* const* d_in, const int* in_sizes, int n_in,
                              void* d_out, int out_size, void* d_ws, size_t ws_size,
                              hipStream_t stream) {
  const float* english = (const float*)d_in[0];
  const float* etok    = (const float*)d_in[1];
  const float* ktoe    = (const float*)d_in[2];
  const float* korean  = (const float*)d_in[3];
  const float* ratios  = (const float*)d_in[4];

  char* ws = (char*)d_ws;
  const size_t OFF_M    = 0;                                   // 8192*1024 = 8 MB
  const size_t OFF_RS   = OFF_M + (size_t)8192 * 1024;         // 4096*4
  const size_t OFF_DIAG = OFF_RS + 4096 * sizeof(float);       // 8*2048*4
  const size_t OFF_REG  = OFF_DIAG + 8 * NB * sizeof(float);   // 2048*4
  const size_t OFF_CNT  = OFF_REG + NB * sizeof(float);        // 4

  unsigned char* M    = (unsigned char*)(ws + OFF_M);
  float* rowsum       = (float*)(ws + OFF_RS);
  float* diag         = (float*)(ws + OFF_DIAG);
  float* reg_partial  = (float*)(ws + OFF_REG);
  unsigned* counter   = (unsigned*)(ws + OFF_CNT);

  k_prep<<<dim3(NB), 256, 0, stream>>>(english, korean, etok, ktoe, ratios,
                                       M, reg_partial, rowsum, counter);
  k_gemm<<<dim3(GEMM_BLOCKS), 256, 0, stream>>>(M, rowsum, diag, reg_partial,
                                                counter, (float*)d_out);
}